// Round 13
// baseline (67.278 us; speedup 1.0000x reference)
//
#include <hip/hip_runtime.h>

// PeerNet: out = relu-MLP with per-feature kNN-mean (k=6, 1D) in the middle.
// B=4096, D=1024, H1=128, H2=64, O=2. All fp32.
//
// Pipeline (4 kernels): prep (W1->f16 hi/lo), gemm1 (MFMA f16 hi/lo),
// sort_window v6 (padded LDS for BOTH s and r_; grid 512 = 128 cols x 4
// window-quarters -> 2 blocks/CU co-resident to hide latency; each block
// redundantly sorts its full column), tail (512 threads, whole-weight LDS).
//
// Lessons: R2 grid.sync ~30us. R11: rolled loops 2x slower; warm sort
// ~8-10us, window ~9-11us. R12: padding s cut conflicts 2.3M->0.8M and
// -1us => conflicts real but latency dominates (VALUBusy 15%, occ 20%,
// 1 block/CU by GRID SIZE). This round: pad r_ too + 2 blocks/CU.

#define NB   4096
#define DIN  1024
#define NH1  128
#define NH2  64

// padded LDS index: 8-word groups spaced 9 words -> bank = (9t+q)%32, free
#define PAD(p) ((p) + ((p) >> 3))

typedef _Float16 f16x8 __attribute__((ext_vector_type(8)));
typedef _Float16 f16x4 __attribute__((ext_vector_type(4)));
typedef float    f32x4 __attribute__((ext_vector_type(4)));

// ---------------------------------------------------------------------------
// prep: W1 [128][1024] fp32 -> Whi/Wlo f16 (hi = rn(w), lo = rn(w - hi)).
// ---------------------------------------------------------------------------
__global__ __launch_bounds__(256) void prep_w1(const float* __restrict__ W1,
                                               _Float16* __restrict__ Whi,
                                               _Float16* __restrict__ Wlo)
{
    const int i = (blockIdx.x * 256 + threadIdx.x) * 4;
    const float4 v = *(const float4*)&W1[i];
    const _Float16 h0 = (_Float16)v.x, h1 = (_Float16)v.y;
    const _Float16 h2 = (_Float16)v.z, h3 = (_Float16)v.w;
    f16x4 hv = {h0, h1, h2, h3};
    f16x4 lv = {(_Float16)(v.x - (float)h0), (_Float16)(v.y - (float)h1),
                (_Float16)(v.z - (float)h2), (_Float16)(v.w - (float)h3)};
    *(f16x4*)&Whi[i] = hv;
    *(f16x4*)&Wlo[i] = lv;
}

// ---------------------------------------------------------------------------
// GEMM1 via MFMA 16x16x32 f16, hi/lo split: h1T[n][m] = relu(x@W1^T + b1)^T.
// Grid 256 blocks x 512 threads (8 waves). Block: 16 batch rows, all 128 n.
// ---------------------------------------------------------------------------
__global__ __launch_bounds__(512) void gemm1_mfma(const float* __restrict__ x,
                                                  const _Float16* __restrict__ Whi,
                                                  const _Float16* __restrict__ Wlo,
                                                  const float* __restrict__ b1,
                                                  float* __restrict__ h1T)
{
    __shared__ _Float16 xhi[16 * 1032];
    __shared__ _Float16 xlo[16 * 1032];
    const int tid = threadIdx.x;
    const int m0  = blockIdx.x * 16;

    {   // stage + convert: thread t -> row t>>5, cols (t&31)*4 + i*128
        const int r  = tid >> 5;
        const int kb = (tid & 31) * 4;
#pragma unroll
        for (int i = 0; i < 8; ++i) {
            const int k = kb + i * 128;
            const float4 v = *(const float4*)&x[(size_t)(m0 + r) * DIN + k];
            const _Float16 h0 = (_Float16)v.x, h1 = (_Float16)v.y;
            const _Float16 h2 = (_Float16)v.z, h3 = (_Float16)v.w;
            f16x4 hv = {h0, h1, h2, h3};
            f16x4 lv = {(_Float16)(v.x - (float)h0), (_Float16)(v.y - (float)h1),
                        (_Float16)(v.z - (float)h2), (_Float16)(v.w - (float)h3)};
            *(f16x4*)&xhi[r * 1032 + k] = hv;
            *(f16x4*)&xlo[r * 1032 + k] = lv;
        }
    }
    __syncthreads();

    const int lane = tid & 63;
    const int w    = tid >> 6;          // 0..7 -> n-tile
    const int n0   = w * 16;
    const int fr   = lane & 15;
    const int fq   = lane >> 4;         // 0..3

    f32x4 acc = {0.f, 0.f, 0.f, 0.f};
    const _Float16* __restrict__ whp = &Whi[(size_t)(n0 + fr) * DIN + fq * 8];
    const _Float16* __restrict__ wlp = &Wlo[(size_t)(n0 + fr) * DIN + fq * 8];
    const _Float16* xh = &xhi[fr * 1032 + fq * 8];
    const _Float16* xl = &xlo[fr * 1032 + fq * 8];

#pragma unroll 4
    for (int ks = 0; ks < 32; ++ks) {
        const int k = ks * 32;
        const f16x8 ah = *(const f16x8*)&xh[k];
        const f16x8 al = *(const f16x8*)&xl[k];
        const f16x8 bh = *(const f16x8*)&whp[k];
        const f16x8 bl = *(const f16x8*)&wlp[k];
        acc = __builtin_amdgcn_mfma_f32_16x16x32_f16(ah, bh, acc, 0, 0, 0);
        acc = __builtin_amdgcn_mfma_f32_16x16x32_f16(ah, bl, acc, 0, 0, 0);
        acc = __builtin_amdgcn_mfma_f32_16x16x32_f16(al, bh, acc, 0, 0, 0);
    }

    const int n = n0 + fr;
    const float bv = b1[n];
    float4 o;
    o.x = fmaxf(acc[0] + bv, 0.f);
    o.y = fmaxf(acc[1] + bv, 0.f);
    o.z = fmaxf(acc[2] + bv, 0.f);
    o.w = fmaxf(acc[3] + bv, 0.f);
    *(float4*)&h1T[(size_t)n * NB + m0 + fq * 4] = o;
}

// ---------------------------------------------------------------------------
// sort_window v6: grid 512 = 128 cols x 4 window-quarters, 512 threads.
// Every block sorts the FULL column (redundant x4 across the column's
// blocks; 2 blocks/CU co-resident -> stalls interleave), then windows its
// own quarter (2 elems/thread).
// Sort: contiguous 8-elem/thread hybrid bitonic, LDS via padded layout
// word(p) = p + (p>>3) (2-way bank aliasing, free).
// Window (bitwise-identical semantics to R10/R12):
//   stage 2: r_[p] per sorted position via greedy 5-step expansion
//            (8 ILP chains/thread; zero-skip when v[7]==0); r_ PADDED too.
//   stage 3: per original element, 12-round 4-way... now 2-way interleaved
//            bsearch on padded s + r_[PAD(lo)] lookup; zeros write 0.
// ---------------------------------------------------------------------------
__global__ __launch_bounds__(512) void sort_window_kernel(const float* __restrict__ h1T,
                                                          float* __restrict__ prtT)
{
    __shared__ float s[PAD(NB - 1) + 2];    // 4608 floats, padded layout
    __shared__ float r_[PAD(NB - 1) + 2];   // padded layout
    const int t    = threadIdx.x;        // 0..511
    const int col  = blockIdx.x >> 2;
    const int seg  = blockIdx.x & 3;
    const float* __restrict__ src = h1T + (size_t)col * NB;

    float v[8];
    {
        const float4 a = *(const float4*)&src[8 * t];
        const float4 b = *(const float4*)&src[8 * t + 4];
        v[0] = a.x; v[1] = a.y; v[2] = a.z; v[3] = a.w;
        v[4] = b.x; v[5] = b.y; v[6] = b.z; v[7] = b.w;
    }

#define CE(a, b, up)                                        \
    {                                                       \
        const float _x = v[a], _y = v[b];                   \
        v[a] = (up) ? fminf(_x, _y) : fmaxf(_x, _y);        \
        v[b] = (up) ? fmaxf(_x, _y) : fminf(_x, _y);        \
    }

    // ---- k = 2 (j=1) ----
    CE(0, 1, true); CE(2, 3, false); CE(4, 5, true); CE(6, 7, false);
    // ---- k = 4 (j=2,1) ----
    CE(0, 2, true);  CE(1, 3, true);  CE(4, 6, false); CE(5, 7, false);
    CE(0, 1, true);  CE(2, 3, true);  CE(4, 5, false); CE(6, 7, false);

    // ---- k = 8..256: uniform direction per thread ----
#pragma unroll
    for (int k = 8; k <= 256; k <<= 1) {
        const bool up = (t & (k >> 3)) == 0;
#pragma unroll
        for (int j = k >> 1; j >= 8; j >>= 1) {
            const int  m       = j >> 3;
            const bool keepmin = (((t & m) == 0) == up);
#pragma unroll
            for (int q = 0; q < 8; ++q) {
                const float p = __shfl_xor(v[q], m);
                v[q] = keepmin ? fminf(v[q], p) : fmaxf(v[q], p);
            }
        }
        CE(0, 4, up); CE(1, 5, up); CE(2, 6, up); CE(3, 7, up);
        CE(0, 2, up); CE(1, 3, up); CE(4, 6, up); CE(5, 7, up);
        CE(0, 1, up); CE(2, 3, up); CE(4, 5, up); CE(6, 7, up);
    }

    // ---- k = 512..4096: LDS (padded) for j>=512, shfl 256..8, intra 4..1 -
#pragma unroll
    for (int k = 512; k <= 4096; k <<= 1) {
        const bool up = (t & (k >> 3)) == 0;
#pragma unroll
        for (int j = k >> 1; j >= 512; j >>= 1) {
            __syncthreads();
            float4 w0 = {v[0], v[1], v[2], v[3]};
            float4 w1 = {v[4], v[5], v[6], v[7]};
            *(float4*)&s[9 * t]     = w0;      // PAD(8t) = 9t
            *(float4*)&s[9 * t + 4] = w1;
            __syncthreads();
            const int tp = t ^ (j >> 3);
            const float4 pa = *(const float4*)&s[9 * tp];
            const float4 pb = *(const float4*)&s[9 * tp + 4];
            const bool keepmin = (((t & (j >> 3)) == 0) == up);
            const float p[8] = {pa.x, pa.y, pa.z, pa.w, pb.x, pb.y, pb.z, pb.w};
#pragma unroll
            for (int q = 0; q < 8; ++q)
                v[q] = keepmin ? fminf(v[q], p[q]) : fmaxf(v[q], p[q]);
        }
#pragma unroll
        for (int j = 256; j >= 8; j >>= 1) {
            const int  m       = j >> 3;
            const bool keepmin = (((t & m) == 0) == up);
#pragma unroll
            for (int q = 0; q < 8; ++q) {
                const float p = __shfl_xor(v[q], m);
                v[q] = keepmin ? fminf(v[q], p) : fmaxf(v[q], p);
            }
        }
        CE(0, 4, up); CE(1, 5, up); CE(2, 6, up); CE(3, 7, up);
        CE(0, 2, up); CE(1, 3, up); CE(4, 6, up); CE(5, 7, up);
        CE(0, 1, up); CE(2, 3, up); CE(4, 5, up); CE(6, 7, up);
    }
#undef CE

    // ---- publish sorted column to LDS (padded) ----
    __syncthreads();
    {
        float4 w0 = {v[0], v[1], v[2], v[3]};
        float4 w1 = {v[4], v[5], v[6], v[7]};
        *(float4*)&s[9 * t]     = w0;
        *(float4*)&s[9 * t + 4] = w1;
    }
    __syncthreads();

    // ---- stage 2: r_[p] for the thread's 8 sorted positions -------------
    if (v[7] == 0.0f) {
        const float4 z4 = {0.f, 0.f, 0.f, 0.f};
        *(float4*)&r_[9 * t]     = z4;
        *(float4*)&r_[9 * t + 4] = z4;
    } else {
        float rr[8];
#pragma unroll
        for (int q = 0; q < 8; ++q) {
            const int  p  = 8 * t + q;
            const float v0 = v[q];
            int l = p, h = p;
            float sum = v0;  // self
#pragma unroll
            for (int it = 0; it < 5; ++it) {
                const int li = (l > 0) ? l - 1 : 0;
                const int ri = (h < NB - 1) ? h + 1 : NB - 1;
                const float sl = s[PAD(li)];
                const float sr = s[PAD(ri)];
                const float dl = (l > 0) ? (v0 - sl) : 1e30f;
                const float dr = (h < NB - 1) ? (sr - v0) : 1e30f;
                if (dl <= dr) { sum += sl; l = li; }
                else          { sum += sr; h = ri; }
            }
            rr[q] = sum * (1.0f / 6.0f);
        }
        const float4 r0 = {rr[0], rr[1], rr[2], rr[3]};
        const float4 r1 = {rr[4], rr[5], rr[6], rr[7]};
        *(float4*)&r_[9 * t]     = r0;
        *(float4*)&r_[9 * t + 4] = r1;
    }
    __syncthreads();

    // ---- stage 3: this block's quarter, interleaved bsearch + lookup ----
    const float z5 = s[PAD(5)];   // ==0 iff column has >= 6 zeros
    float v0[2];
    bool  zs[2];
    float key[2];
    int   lo[2], hi[2];
#pragma unroll
    for (int w = 0; w < 2; ++w) {
        const int e = seg * 1024 + t + w * 512;
        v0[w]  = src[e];
        zs[w]  = (v0[w] == 0.0f) && (z5 == 0.0f);
        key[w] = zs[w] ? -1.0f : v0[w];
        lo[w]  = 0;
        hi[w]  = NB;
    }
#pragma unroll
    for (int step = 0; step < 12; ++step) {
#pragma unroll
        for (int w = 0; w < 2; ++w) {
            const int mid = (lo[w] + hi[w]) >> 1;
            const float sv = s[PAD(mid)];
            if (sv < key[w]) lo[w] = mid + 1; else hi[w] = mid;
        }
    }
#pragma unroll
    for (int w = 0; w < 2; ++w) {
        const int e = seg * 1024 + t + w * 512;
        const float res = zs[w] ? 0.0f : r_[PAD(lo[w])];
        prtT[(size_t)col * NB + e] = res;
    }
}

// ---------------------------------------------------------------------------
// Fused tail (512 threads): out = (relu(relu(pr@Wpr^T+bpr)@W2^T+b2))@Wo^T+bo
// Whole Wpr and W2 staged once each. 8 waves/CU (2/SIMD).
// ---------------------------------------------------------------------------
__global__ __launch_bounds__(512) void tail_kernel(const float* __restrict__ AT,
                                                   const float* __restrict__ Wpr,
                                                   const float* __restrict__ bpr,
                                                   const float* __restrict__ W2,
                                                   const float* __restrict__ b2,
                                                   const float* __restrict__ Wo,
                                                   const float* __restrict__ bo,
                                                   float* __restrict__ out)
{
    __shared__ float As[NH1 * 17];    // A^T tile [k=128][m=16]
    __shared__ float Bs[NH1 * 132];   // Wpr full [k][n]; reused for W2 [nn][68]
    __shared__ float Ps[16 * 132];    // pr tile [m][n=128]
    __shared__ float Rs[32 * 32];     // out reduction [g][m*2+o]
    const int tid = threadIdx.x;
    const int m0  = blockIdx.x * 16;

    {   // load A tile: As[k][m] = AT[k*NB + m0 + m]; 512 float4, 1/thread
        const int row = tid >> 2;
        const int f   = (tid & 3) * 4;
        const float4 v = *(const float4*)&AT[(size_t)row * NB + m0 + f];
        As[row * 17 + f + 0] = v.x;
        As[row * 17 + f + 1] = v.y;
        As[row * 17 + f + 2] = v.z;
        As[row * 17 + f + 3] = v.w;
    }
    {   // stage FULL Wpr: Bs[k][n] = Wpr[n][k]; n = tid>>2, k-quarter = tid&3
        const int n  = tid >> 2;
        const int kb = (tid & 3) * 32;
#pragma unroll
        for (int i4 = 0; i4 < 8; ++i4) {
            const float4 v = *(const float4*)&Wpr[(size_t)n * NH1 + kb + i4 * 4];
            Bs[(kb + i4 * 4 + 0) * 132 + n] = v.x;
            Bs[(kb + i4 * 4 + 1) * 132 + n] = v.y;
            Bs[(kb + i4 * 4 + 2) * 132 + n] = v.z;
            Bs[(kb + i4 * 4 + 3) * 132 + n] = v.w;
        }
    }
    __syncthreads();

    const int m  = tid & 15;
    const int g  = tid >> 4;     // 0..31
    const int n0 = g * 4;

    float acc[4] = {0.f, 0.f, 0.f, 0.f};
#pragma unroll 8
    for (int kk = 0; kk < NH1; ++kk) {
        const float a  = As[kk * 17 + m];
        const float4 b = *(const float4*)&Bs[kk * 132 + n0];
        acc[0] = fmaf(a, b.x, acc[0]);
        acc[1] = fmaf(a, b.y, acc[1]);
        acc[2] = fmaf(a, b.z, acc[2]);
        acc[3] = fmaf(a, b.w, acc[3]);
    }
#pragma unroll
    for (int j = 0; j < 4; ++j)
        Ps[m * 132 + n0 + j] = fmaxf(acc[j] + bpr[n0 + j], 0.f);
    __syncthreads();

    {   // stage FULL W2 (reuse Bs): Bs[nn][j2] = W2[j2][nn], stride 68
        const int j2 = tid >> 3;
        const int nb = (tid & 7) * 16;
#pragma unroll
        for (int i4 = 0; i4 < 4; ++i4) {
            const float4 v = *(const float4*)&W2[(size_t)j2 * NH1 + nb + i4 * 4];
            Bs[(nb + i4 * 4 + 0) * 68 + j2] = v.x;
            Bs[(nb + i4 * 4 + 1) * 68 + j2] = v.y;
            Bs[(nb + i4 * 4 + 2) * 68 + j2] = v.z;
            Bs[(nb + i4 * 4 + 3) * 68 + j2] = v.w;
        }
    }
    __syncthreads();

    const int j0 = g * 2;
    float acc2[2] = {0.f, 0.f};
#pragma unroll 8
    for (int nn = 0; nn < NH1; ++nn) {
        const float p  = Ps[m * 132 + nn];
        const float2 w = *(const float2*)&Bs[nn * 68 + j0];
        acc2[0] = fmaf(p, w.x, acc2[0]);
        acc2[1] = fmaf(p, w.y, acc2[1]);
    }

    float po0 = 0.f, po1 = 0.f;
#pragma unroll
    for (int j = 0; j < 2; ++j) {
        const float h = fmaxf(acc2[j] + b2[j0 + j], 0.f);
        po0 = fmaf(h, Wo[j0 + j], po0);
        po1 = fmaf(h, Wo[NH2 + j0 + j], po1);
    }
    Rs[g * 32 + m * 2 + 0] = po0;
    Rs[g * 32 + m * 2 + 1] = po1;
    __syncthreads();
    if (tid < 32) {
        const int mm = tid >> 1, o = tid & 1;
        float sum = 0.f;
#pragma unroll
        for (int gg = 0; gg < 32; ++gg) sum += Rs[gg * 32 + mm * 2 + o];
        out[(size_t)(m0 + mm) * 2 + o] = sum + bo[o];
    }
}

extern "C" void kernel_launch(void* const* d_in, const int* in_sizes, int n_in,
                              void* d_out, int out_size, void* d_ws, size_t ws_size,
                              hipStream_t stream)
{
    const float* x   = (const float*)d_in[0];
    const float* W1  = (const float*)d_in[1];
    const float* b1  = (const float*)d_in[2];
    const float* Wpr = (const float*)d_in[3];
    const float* bpr = (const float*)d_in[4];
    const float* W2  = (const float*)d_in[5];
    const float* b2  = (const float*)d_in[6];
    const float* Wo  = (const float*)d_in[7];
    const float* bo  = (const float*)d_in[8];

    float* ws     = (float*)d_ws;
    float* h1T    = ws;                               // [128][4096]  2 MB
    float* prtT   = h1T + NH1 * NB;                   // [128][4096]  2 MB
    _Float16* Whi = (_Float16*)(prtT + NH1 * NB);     // [128][1024]  256 KB
    _Float16* Wlo = Whi + NH1 * DIN;                  // [128][1024]  256 KB

    prep_w1<<<dim3(NH1 * DIN / 4 / 256), 256, 0, stream>>>(W1, Whi, Wlo);
    gemm1_mfma<<<dim3(NB / 16), 512, 0, stream>>>(x, Whi, Wlo, b1, h1T);
    sort_window_kernel<<<dim3(NH1 * 4), 512, 0, stream>>>(h1T, prtT);
    tail_kernel<<<dim3(NB / 16), 512, 0, stream>>>(prtT, Wpr, bpr, W2, b2, Wo, bo,
                                                   (float*)d_out);
}

// Round 14
// 57.539 us; speedup vs baseline: 1.1693x; 1.1693x over previous
//
#include <hip/hip_runtime.h>

// PeerNet: out = relu-MLP with per-feature kNN-mean (k=6, 1D) in the middle.
// B=4096, D=1024, H1=128, H2=64, O=2. All fp32.
//
// Pipeline (4 kernels): prep (W1->f16 hi/lo), gemm1 (MFMA f16 hi/lo),
// sort_window v7 (grid 256 = 128 cols x 2 halves, BOTH s and r_ in the
// 9-stride padded LDS layout), tail (512 threads, whole-weight LDS).
//
// Lessons: R2 grid.sync ~30us. R11: rolled loops 2x slower. R12: padding
// s cut conflicts 2.3M->0.8M, -1us. R13: grid 512 (2 blocks/CU, redundant
// sort x4/column) REGRESSED +10us despite VALUBusy 15->30% => sort is
// throughput-bound, redundant sort work is paid for real; grid 256 with
// one sort per half-column is the proven partitioning. This round = R12
// partitioning + R13's r_ padding (the untested good combo).

#define NB   4096
#define DIN  1024
#define NH1  128
#define NH2  64

// padded LDS index: 8-word groups spaced 9 words -> bank = (9t+q)%32, free
#define PAD(p) ((p) + ((p) >> 3))

typedef _Float16 f16x8 __attribute__((ext_vector_type(8)));
typedef _Float16 f16x4 __attribute__((ext_vector_type(4)));
typedef float    f32x4 __attribute__((ext_vector_type(4)));

// ---------------------------------------------------------------------------
// prep: W1 [128][1024] fp32 -> Whi/Wlo f16 (hi = rn(w), lo = rn(w - hi)).
// ---------------------------------------------------------------------------
__global__ __launch_bounds__(256) void prep_w1(const float* __restrict__ W1,
                                               _Float16* __restrict__ Whi,
                                               _Float16* __restrict__ Wlo)
{
    const int i = (blockIdx.x * 256 + threadIdx.x) * 4;
    const float4 v = *(const float4*)&W1[i];
    const _Float16 h0 = (_Float16)v.x, h1 = (_Float16)v.y;
    const _Float16 h2 = (_Float16)v.z, h3 = (_Float16)v.w;
    f16x4 hv = {h0, h1, h2, h3};
    f16x4 lv = {(_Float16)(v.x - (float)h0), (_Float16)(v.y - (float)h1),
                (_Float16)(v.z - (float)h2), (_Float16)(v.w - (float)h3)};
    *(f16x4*)&Whi[i] = hv;
    *(f16x4*)&Wlo[i] = lv;
}

// ---------------------------------------------------------------------------
// GEMM1 via MFMA 16x16x32 f16, hi/lo split: h1T[n][m] = relu(x@W1^T + b1)^T.
// Grid 256 blocks x 512 threads (8 waves). Block: 16 batch rows, all 128 n.
// ---------------------------------------------------------------------------
__global__ __launch_bounds__(512) void gemm1_mfma(const float* __restrict__ x,
                                                  const _Float16* __restrict__ Whi,
                                                  const _Float16* __restrict__ Wlo,
                                                  const float* __restrict__ b1,
                                                  float* __restrict__ h1T)
{
    __shared__ _Float16 xhi[16 * 1032];
    __shared__ _Float16 xlo[16 * 1032];
    const int tid = threadIdx.x;
    const int m0  = blockIdx.x * 16;

    {   // stage + convert: thread t -> row t>>5, cols (t&31)*4 + i*128
        const int r  = tid >> 5;
        const int kb = (tid & 31) * 4;
#pragma unroll
        for (int i = 0; i < 8; ++i) {
            const int k = kb + i * 128;
            const float4 v = *(const float4*)&x[(size_t)(m0 + r) * DIN + k];
            const _Float16 h0 = (_Float16)v.x, h1 = (_Float16)v.y;
            const _Float16 h2 = (_Float16)v.z, h3 = (_Float16)v.w;
            f16x4 hv = {h0, h1, h2, h3};
            f16x4 lv = {(_Float16)(v.x - (float)h0), (_Float16)(v.y - (float)h1),
                        (_Float16)(v.z - (float)h2), (_Float16)(v.w - (float)h3)};
            *(f16x4*)&xhi[r * 1032 + k] = hv;
            *(f16x4*)&xlo[r * 1032 + k] = lv;
        }
    }
    __syncthreads();

    const int lane = tid & 63;
    const int w    = tid >> 6;          // 0..7 -> n-tile
    const int n0   = w * 16;
    const int fr   = lane & 15;
    const int fq   = lane >> 4;         // 0..3

    f32x4 acc = {0.f, 0.f, 0.f, 0.f};
    const _Float16* __restrict__ whp = &Whi[(size_t)(n0 + fr) * DIN + fq * 8];
    const _Float16* __restrict__ wlp = &Wlo[(size_t)(n0 + fr) * DIN + fq * 8];
    const _Float16* xh = &xhi[fr * 1032 + fq * 8];
    const _Float16* xl = &xlo[fr * 1032 + fq * 8];

#pragma unroll 4
    for (int ks = 0; ks < 32; ++ks) {
        const int k = ks * 32;
        const f16x8 ah = *(const f16x8*)&xh[k];
        const f16x8 al = *(const f16x8*)&xl[k];
        const f16x8 bh = *(const f16x8*)&whp[k];
        const f16x8 bl = *(const f16x8*)&wlp[k];
        acc = __builtin_amdgcn_mfma_f32_16x16x32_f16(ah, bh, acc, 0, 0, 0);
        acc = __builtin_amdgcn_mfma_f32_16x16x32_f16(ah, bl, acc, 0, 0, 0);
        acc = __builtin_amdgcn_mfma_f32_16x16x32_f16(al, bh, acc, 0, 0, 0);
    }

    const int n = n0 + fr;
    const float bv = b1[n];
    float4 o;
    o.x = fmaxf(acc[0] + bv, 0.f);
    o.y = fmaxf(acc[1] + bv, 0.f);
    o.z = fmaxf(acc[2] + bv, 0.f);
    o.w = fmaxf(acc[3] + bv, 0.f);
    *(float4*)&h1T[(size_t)n * NB + m0 + fq * 4] = o;
}

// ---------------------------------------------------------------------------
// sort_window v7: grid 256 = 128 cols x 2 halves, 512 threads.
// Sort: contiguous 8-elem/thread hybrid bitonic; all LDS traffic through
// the padded layout word(p) = p + (p>>3) (2-way bank aliasing, free).
// Window (bitwise-identical semantics to R10/R12):
//   stage 2: r_[p] per sorted position via greedy 5-step expansion
//            (8 ILP chains/thread; zero-skip when v[7]==0); r_ padded.
//   stage 3: per original element (4/thread), 12-round 4-way interleaved
//            bsearch on padded s + r_[PAD(lo)] lookup; zeros write 0.
// ---------------------------------------------------------------------------
__global__ __launch_bounds__(512) void sort_window_kernel(const float* __restrict__ h1T,
                                                          float* __restrict__ prtT)
{
    __shared__ float s[PAD(NB - 1) + 2];    // padded layout
    __shared__ float r_[PAD(NB - 1) + 2];   // padded layout
    const int t    = threadIdx.x;        // 0..511
    const int col  = blockIdx.x >> 1;
    const int half = blockIdx.x & 1;
    const float* __restrict__ src = h1T + (size_t)col * NB;

    float v[8];
    {
        const float4 a = *(const float4*)&src[8 * t];
        const float4 b = *(const float4*)&src[8 * t + 4];
        v[0] = a.x; v[1] = a.y; v[2] = a.z; v[3] = a.w;
        v[4] = b.x; v[5] = b.y; v[6] = b.z; v[7] = b.w;
    }

#define CE(a, b, up)                                        \
    {                                                       \
        const float _x = v[a], _y = v[b];                   \
        v[a] = (up) ? fminf(_x, _y) : fmaxf(_x, _y);        \
        v[b] = (up) ? fmaxf(_x, _y) : fminf(_x, _y);        \
    }

    // ---- k = 2 (j=1) ----
    CE(0, 1, true); CE(2, 3, false); CE(4, 5, true); CE(6, 7, false);
    // ---- k = 4 (j=2,1) ----
    CE(0, 2, true);  CE(1, 3, true);  CE(4, 6, false); CE(5, 7, false);
    CE(0, 1, true);  CE(2, 3, true);  CE(4, 5, false); CE(6, 7, false);

    // ---- k = 8..256: uniform direction per thread ----
#pragma unroll
    for (int k = 8; k <= 256; k <<= 1) {
        const bool up = (t & (k >> 3)) == 0;
#pragma unroll
        for (int j = k >> 1; j >= 8; j >>= 1) {
            const int  m       = j >> 3;
            const bool keepmin = (((t & m) == 0) == up);
#pragma unroll
            for (int q = 0; q < 8; ++q) {
                const float p = __shfl_xor(v[q], m);
                v[q] = keepmin ? fminf(v[q], p) : fmaxf(v[q], p);
            }
        }
        CE(0, 4, up); CE(1, 5, up); CE(2, 6, up); CE(3, 7, up);
        CE(0, 2, up); CE(1, 3, up); CE(4, 6, up); CE(5, 7, up);
        CE(0, 1, up); CE(2, 3, up); CE(4, 5, up); CE(6, 7, up);
    }

    // ---- k = 512..4096: LDS (padded) for j>=512, shfl 256..8, intra 4..1 -
#pragma unroll
    for (int k = 512; k <= 4096; k <<= 1) {
        const bool up = (t & (k >> 3)) == 0;
#pragma unroll
        for (int j = k >> 1; j >= 512; j >>= 1) {
            __syncthreads();
            float4 w0 = {v[0], v[1], v[2], v[3]};
            float4 w1 = {v[4], v[5], v[6], v[7]};
            *(float4*)&s[9 * t]     = w0;      // PAD(8t) = 9t
            *(float4*)&s[9 * t + 4] = w1;
            __syncthreads();
            const int tp = t ^ (j >> 3);
            const float4 pa = *(const float4*)&s[9 * tp];
            const float4 pb = *(const float4*)&s[9 * tp + 4];
            const bool keepmin = (((t & (j >> 3)) == 0) == up);
            const float p[8] = {pa.x, pa.y, pa.z, pa.w, pb.x, pb.y, pb.z, pb.w};
#pragma unroll
            for (int q = 0; q < 8; ++q)
                v[q] = keepmin ? fminf(v[q], p[q]) : fmaxf(v[q], p[q]);
        }
#pragma unroll
        for (int j = 256; j >= 8; j >>= 1) {
            const int  m       = j >> 3;
            const bool keepmin = (((t & m) == 0) == up);
#pragma unroll
            for (int q = 0; q < 8; ++q) {
                const float p = __shfl_xor(v[q], m);
                v[q] = keepmin ? fminf(v[q], p) : fmaxf(v[q], p);
            }
        }
        CE(0, 4, up); CE(1, 5, up); CE(2, 6, up); CE(3, 7, up);
        CE(0, 2, up); CE(1, 3, up); CE(4, 6, up); CE(5, 7, up);
        CE(0, 1, up); CE(2, 3, up); CE(4, 5, up); CE(6, 7, up);
    }
#undef CE

    // ---- publish sorted column to LDS (padded) ----
    __syncthreads();
    {
        float4 w0 = {v[0], v[1], v[2], v[3]};
        float4 w1 = {v[4], v[5], v[6], v[7]};
        *(float4*)&s[9 * t]     = w0;
        *(float4*)&s[9 * t + 4] = w1;
    }
    __syncthreads();

    // ---- stage 2: r_[p] for the thread's 8 sorted positions -------------
    if (v[7] == 0.0f) {
        const float4 z4 = {0.f, 0.f, 0.f, 0.f};
        *(float4*)&r_[9 * t]     = z4;
        *(float4*)&r_[9 * t + 4] = z4;
    } else {
        float rr[8];
#pragma unroll
        for (int q = 0; q < 8; ++q) {
            const int  p  = 8 * t + q;
            const float v0 = v[q];
            int l = p, h = p;
            float sum = v0;  // self
#pragma unroll
            for (int it = 0; it < 5; ++it) {
                const int li = (l > 0) ? l - 1 : 0;
                const int ri = (h < NB - 1) ? h + 1 : NB - 1;
                const float sl = s[PAD(li)];
                const float sr = s[PAD(ri)];
                const float dl = (l > 0) ? (v0 - sl) : 1e30f;
                const float dr = (h < NB - 1) ? (sr - v0) : 1e30f;
                if (dl <= dr) { sum += sl; l = li; }
                else          { sum += sr; h = ri; }
            }
            rr[q] = sum * (1.0f / 6.0f);
        }
        const float4 r0 = {rr[0], rr[1], rr[2], rr[3]};
        const float4 r1 = {rr[4], rr[5], rr[6], rr[7]};
        *(float4*)&r_[9 * t]     = r0;
        *(float4*)&r_[9 * t + 4] = r1;
    }
    __syncthreads();

    // ---- stage 3: per original element, interleaved bsearch + lookup ----
    const float z5 = s[PAD(5)];   // ==0 iff column has >= 6 zeros
    float v0[4];
    bool  zs[4];
    float key[4];
    int   lo[4], hi[4];
#pragma unroll
    for (int w = 0; w < 4; ++w) {
        const int e = half * 2048 + t + w * 512;
        v0[w]  = src[e];
        zs[w]  = (v0[w] == 0.0f) && (z5 == 0.0f);
        key[w] = zs[w] ? -1.0f : v0[w];
        lo[w]  = 0;
        hi[w]  = NB;
    }
#pragma unroll
    for (int step = 0; step < 12; ++step) {
#pragma unroll
        for (int w = 0; w < 4; ++w) {
            const int mid = (lo[w] + hi[w]) >> 1;
            const float sv = s[PAD(mid)];
            if (sv < key[w]) lo[w] = mid + 1; else hi[w] = mid;
        }
    }
#pragma unroll
    for (int w = 0; w < 4; ++w) {
        const int e = half * 2048 + t + w * 512;
        const float res = zs[w] ? 0.0f : r_[PAD(lo[w])];
        prtT[(size_t)col * NB + e] = res;
    }
}

// ---------------------------------------------------------------------------
// Fused tail (512 threads): out = (relu(relu(pr@Wpr^T+bpr)@W2^T+b2))@Wo^T+bo
// Whole Wpr and W2 staged once each. 8 waves/CU (2/SIMD).
// ---------------------------------------------------------------------------
__global__ __launch_bounds__(512) void tail_kernel(const float* __restrict__ AT,
                                                   const float* __restrict__ Wpr,
                                                   const float* __restrict__ bpr,
                                                   const float* __restrict__ W2,
                                                   const float* __restrict__ b2,
                                                   const float* __restrict__ Wo,
                                                   const float* __restrict__ bo,
                                                   float* __restrict__ out)
{
    __shared__ float As[NH1 * 17];    // A^T tile [k=128][m=16]
    __shared__ float Bs[NH1 * 132];   // Wpr full [k][n]; reused for W2 [nn][68]
    __shared__ float Ps[16 * 132];    // pr tile [m][n=128]
    __shared__ float Rs[32 * 32];     // out reduction [g][m*2+o]
    const int tid = threadIdx.x;
    const int m0  = blockIdx.x * 16;

    {   // load A tile: As[k][m] = AT[k*NB + m0 + m]; 512 float4, 1/thread
        const int row = tid >> 2;
        const int f   = (tid & 3) * 4;
        const float4 v = *(const float4*)&AT[(size_t)row * NB + m0 + f];
        As[row * 17 + f + 0] = v.x;
        As[row * 17 + f + 1] = v.y;
        As[row * 17 + f + 2] = v.z;
        As[row * 17 + f + 3] = v.w;
    }
    {   // stage FULL Wpr: Bs[k][n] = Wpr[n][k]; n = tid>>2, k-quarter = tid&3
        const int n  = tid >> 2;
        const int kb = (tid & 3) * 32;
#pragma unroll
        for (int i4 = 0; i4 < 8; ++i4) {
            const float4 v = *(const float4*)&Wpr[(size_t)n * NH1 + kb + i4 * 4];
            Bs[(kb + i4 * 4 + 0) * 132 + n] = v.x;
            Bs[(kb + i4 * 4 + 1) * 132 + n] = v.y;
            Bs[(kb + i4 * 4 + 2) * 132 + n] = v.z;
            Bs[(kb + i4 * 4 + 3) * 132 + n] = v.w;
        }
    }
    __syncthreads();

    const int m  = tid & 15;
    const int g  = tid >> 4;     // 0..31
    const int n0 = g * 4;

    float acc[4] = {0.f, 0.f, 0.f, 0.f};
#pragma unroll 8
    for (int kk = 0; kk < NH1; ++kk) {
        const float a  = As[kk * 17 + m];
        const float4 b = *(const float4*)&Bs[kk * 132 + n0];
        acc[0] = fmaf(a, b.x, acc[0]);
        acc[1] = fmaf(a, b.y, acc[1]);
        acc[2] = fmaf(a, b.z, acc[2]);
        acc[3] = fmaf(a, b.w, acc[3]);
    }
#pragma unroll
    for (int j = 0; j < 4; ++j)
        Ps[m * 132 + n0 + j] = fmaxf(acc[j] + bpr[n0 + j], 0.f);
    __syncthreads();

    {   // stage FULL W2 (reuse Bs): Bs[nn][j2] = W2[j2][nn], stride 68
        const int j2 = tid >> 3;
        const int nb = (tid & 7) * 16;
#pragma unroll
        for (int i4 = 0; i4 < 4; ++i4) {
            const float4 v = *(const float4*)&W2[(size_t)j2 * NH1 + nb + i4 * 4];
            Bs[(nb + i4 * 4 + 0) * 68 + j2] = v.x;
            Bs[(nb + i4 * 4 + 1) * 68 + j2] = v.y;
            Bs[(nb + i4 * 4 + 2) * 68 + j2] = v.z;
            Bs[(nb + i4 * 4 + 3) * 68 + j2] = v.w;
        }
    }
    __syncthreads();

    const int j0 = g * 2;
    float acc2[2] = {0.f, 0.f};
#pragma unroll 8
    for (int nn = 0; nn < NH1; ++nn) {
        const float p  = Ps[m * 132 + nn];
        const float2 w = *(const float2*)&Bs[nn * 68 + j0];
        acc2[0] = fmaf(p, w.x, acc2[0]);
        acc2[1] = fmaf(p, w.y, acc2[1]);
    }

    float po0 = 0.f, po1 = 0.f;
#pragma unroll
    for (int j = 0; j < 2; ++j) {
        const float h = fmaxf(acc2[j] + b2[j0 + j], 0.f);
        po0 = fmaf(h, Wo[j0 + j], po0);
        po1 = fmaf(h, Wo[NH2 + j0 + j], po1);
    }
    Rs[g * 32 + m * 2 + 0] = po0;
    Rs[g * 32 + m * 2 + 1] = po1;
    __syncthreads();
    if (tid < 32) {
        const int mm = tid >> 1, o = tid & 1;
        float sum = 0.f;
#pragma unroll
        for (int gg = 0; gg < 32; ++gg) sum += Rs[gg * 32 + mm * 2 + o];
        out[(size_t)(m0 + mm) * 2 + o] = sum + bo[o];
    }
}

extern "C" void kernel_launch(void* const* d_in, const int* in_sizes, int n_in,
                              void* d_out, int out_size, void* d_ws, size_t ws_size,
                              hipStream_t stream)
{
    const float* x   = (const float*)d_in[0];
    const float* W1  = (const float*)d_in[1];
    const float* b1  = (const float*)d_in[2];
    const float* Wpr = (const float*)d_in[3];
    const float* bpr = (const float*)d_in[4];
    const float* W2  = (const float*)d_in[5];
    const float* b2  = (const float*)d_in[6];
    const float* Wo  = (const float*)d_in[7];
    const float* bo  = (const float*)d_in[8];

    float* ws     = (float*)d_ws;
    float* h1T    = ws;                               // [128][4096]  2 MB
    float* prtT   = h1T + NH1 * NB;                   // [128][4096]  2 MB
    _Float16* Whi = (_Float16*)(prtT + NH1 * NB);     // [128][1024]  256 KB
    _Float16* Wlo = Whi + NH1 * DIN;                  // [128][1024]  256 KB

    prep_w1<<<dim3(NH1 * DIN / 4 / 256), 256, 0, stream>>>(W1, Whi, Wlo);
    gemm1_mfma<<<dim3(NB / 16), 512, 0, stream>>>(x, Whi, Wlo, b1, h1T);
    sort_window_kernel<<<dim3(NH1 * 2), 512, 0, stream>>>(h1T, prtT);
    tail_kernel<<<dim3(NB / 16), 512, 0, stream>>>(prtT, Wpr, bpr, W2, b2, Wo, bo,
                                                   (float*)d_out);
}

// Round 15
// 52.559 us; speedup vs baseline: 1.2801x; 1.0947x over previous
//
#include <hip/hip_runtime.h>

// PeerNet: out = relu-MLP with per-feature kNN-mean (k=6, 1D) in the middle.
// B=4096, D=1024, H1=128, H2=64, O=2. All fp32.
//
// Pipeline (3 kernels): gemm1 (MFMA f16 hi/lo with IN-LOOP W1 conversion --
// fp32 W1 row read = 32B/lane/k-step, same bytes as Whi+Whlo, so prep kernel
// and its boundary are deleted), sort_window v7 (padded LDS), tail (512 thr).
//
// Lessons: R2 grid.sync ~30us. R11: rolled loops 2x slower. R12: s-padding
// -65% conflicts, -1us. R13: redundant sort x2 regresses (throughput-bound).
// R14: r_ padding null -> sort_window closed at ~19us in-graph.

#define NB   4096
#define DIN  1024
#define NH1  128
#define NH2  64

// padded LDS index: 8-word groups spaced 9 words -> bank = (9t+q)%32, free
#define PAD(p) ((p) + ((p) >> 3))

typedef _Float16 f16x8 __attribute__((ext_vector_type(8)));
typedef _Float16 f16x4 __attribute__((ext_vector_type(4)));
typedef float    f32x4 __attribute__((ext_vector_type(4)));

// ---------------------------------------------------------------------------
// GEMM1 via MFMA 16x16x32 f16, hi/lo split: h1T[n][m] = relu(x@W1^T + b1)^T.
// Grid 256 blocks x 512 threads (8 waves). Block: 16 batch rows, all 128 n.
// W1 is read as fp32 and hi/lo-split in-register per k-step (same 32B/lane
// as the old Whi+Wlo reads; conversion identical to the old prep kernel ->
// bitwise-identical h1T).
// ---------------------------------------------------------------------------
__global__ __launch_bounds__(512) void gemm1_mfma(const float* __restrict__ x,
                                                  const float* __restrict__ W1,
                                                  const float* __restrict__ b1,
                                                  float* __restrict__ h1T)
{
    __shared__ _Float16 xhi[16 * 1032];
    __shared__ _Float16 xlo[16 * 1032];
    const int tid = threadIdx.x;
    const int m0  = blockIdx.x * 16;

    {   // stage + convert: thread t -> row t>>5, cols (t&31)*4 + i*128
        const int r  = tid >> 5;
        const int kb = (tid & 31) * 4;
#pragma unroll
        for (int i = 0; i < 8; ++i) {
            const int k = kb + i * 128;
            const float4 v = *(const float4*)&x[(size_t)(m0 + r) * DIN + k];
            const _Float16 h0 = (_Float16)v.x, h1 = (_Float16)v.y;
            const _Float16 h2 = (_Float16)v.z, h3 = (_Float16)v.w;
            f16x4 hv = {h0, h1, h2, h3};
            f16x4 lv = {(_Float16)(v.x - (float)h0), (_Float16)(v.y - (float)h1),
                        (_Float16)(v.z - (float)h2), (_Float16)(v.w - (float)h3)};
            *(f16x4*)&xhi[r * 1032 + k] = hv;
            *(f16x4*)&xlo[r * 1032 + k] = lv;
        }
    }
    __syncthreads();

    const int lane = tid & 63;
    const int w    = tid >> 6;          // 0..7 -> n-tile
    const int n0   = w * 16;
    const int fr   = lane & 15;
    const int fq   = lane >> 4;         // 0..3

    f32x4 acc = {0.f, 0.f, 0.f, 0.f};
    const float* __restrict__ wp = &W1[(size_t)(n0 + fr) * DIN + fq * 8];
    const _Float16* xh = &xhi[fr * 1032 + fq * 8];
    const _Float16* xl = &xlo[fr * 1032 + fq * 8];

#pragma unroll 4
    for (int ks = 0; ks < 32; ++ks) {
        const int k = ks * 32;
        const f16x8 ah = *(const f16x8*)&xh[k];
        const f16x8 al = *(const f16x8*)&xl[k];
        // load W1 fragment as fp32 (32B, same as old Whi+Wlo) and split
        const float4 wa = *(const float4*)&wp[k];
        const float4 wb = *(const float4*)&wp[k + 4];
        const float wf[8] = {wa.x, wa.y, wa.z, wa.w, wb.x, wb.y, wb.z, wb.w};
        f16x8 bh, bl;
#pragma unroll
        for (int q = 0; q < 8; ++q) {
            const _Float16 h = (_Float16)wf[q];
            bh[q] = h;
            bl[q] = (_Float16)(wf[q] - (float)h);
        }
        acc = __builtin_amdgcn_mfma_f32_16x16x32_f16(ah, bh, acc, 0, 0, 0);
        acc = __builtin_amdgcn_mfma_f32_16x16x32_f16(ah, bl, acc, 0, 0, 0);
        acc = __builtin_amdgcn_mfma_f32_16x16x32_f16(al, bh, acc, 0, 0, 0);
    }

    const int n = n0 + fr;
    const float bv = b1[n];
    float4 o;
    o.x = fmaxf(acc[0] + bv, 0.f);
    o.y = fmaxf(acc[1] + bv, 0.f);
    o.z = fmaxf(acc[2] + bv, 0.f);
    o.w = fmaxf(acc[3] + bv, 0.f);
    *(float4*)&h1T[(size_t)n * NB + m0 + fq * 4] = o;
}

// ---------------------------------------------------------------------------
// sort_window v7: grid 256 = 128 cols x 2 halves, 512 threads.
// Sort: contiguous 8-elem/thread hybrid bitonic; all LDS traffic through
// the padded layout word(p) = p + (p>>3) (2-way bank aliasing, free).
// Window: stage 2 r_[p] per sorted position (8 ILP chains; zero-skip);
// stage 3 per original element 12-round 4-way interleaved bsearch + lookup.
// ---------------------------------------------------------------------------
__global__ __launch_bounds__(512) void sort_window_kernel(const float* __restrict__ h1T,
                                                          float* __restrict__ prtT)
{
    __shared__ float s[PAD(NB - 1) + 2];    // padded layout
    __shared__ float r_[PAD(NB - 1) + 2];   // padded layout
    const int t    = threadIdx.x;        // 0..511
    const int col  = blockIdx.x >> 1;
    const int half = blockIdx.x & 1;
    const float* __restrict__ src = h1T + (size_t)col * NB;

    float v[8];
    {
        const float4 a = *(const float4*)&src[8 * t];
        const float4 b = *(const float4*)&src[8 * t + 4];
        v[0] = a.x; v[1] = a.y; v[2] = a.z; v[3] = a.w;
        v[4] = b.x; v[5] = b.y; v[6] = b.z; v[7] = b.w;
    }

#define CE(a, b, up)                                        \
    {                                                       \
        const float _x = v[a], _y = v[b];                   \
        v[a] = (up) ? fminf(_x, _y) : fmaxf(_x, _y);        \
        v[b] = (up) ? fmaxf(_x, _y) : fminf(_x, _y);        \
    }

    // ---- k = 2 (j=1) ----
    CE(0, 1, true); CE(2, 3, false); CE(4, 5, true); CE(6, 7, false);
    // ---- k = 4 (j=2,1) ----
    CE(0, 2, true);  CE(1, 3, true);  CE(4, 6, false); CE(5, 7, false);
    CE(0, 1, true);  CE(2, 3, true);  CE(4, 5, false); CE(6, 7, false);

    // ---- k = 8..256: uniform direction per thread ----
#pragma unroll
    for (int k = 8; k <= 256; k <<= 1) {
        const bool up = (t & (k >> 3)) == 0;
#pragma unroll
        for (int j = k >> 1; j >= 8; j >>= 1) {
            const int  m       = j >> 3;
            const bool keepmin = (((t & m) == 0) == up);
#pragma unroll
            for (int q = 0; q < 8; ++q) {
                const float p = __shfl_xor(v[q], m);
                v[q] = keepmin ? fminf(v[q], p) : fmaxf(v[q], p);
            }
        }
        CE(0, 4, up); CE(1, 5, up); CE(2, 6, up); CE(3, 7, up);
        CE(0, 2, up); CE(1, 3, up); CE(4, 6, up); CE(5, 7, up);
        CE(0, 1, up); CE(2, 3, up); CE(4, 5, up); CE(6, 7, up);
    }

    // ---- k = 512..4096: LDS (padded) for j>=512, shfl 256..8, intra 4..1 -
#pragma unroll
    for (int k = 512; k <= 4096; k <<= 1) {
        const bool up = (t & (k >> 3)) == 0;
#pragma unroll
        for (int j = k >> 1; j >= 512; j >>= 1) {
            __syncthreads();
            float4 w0 = {v[0], v[1], v[2], v[3]};
            float4 w1 = {v[4], v[5], v[6], v[7]};
            *(float4*)&s[9 * t]     = w0;      // PAD(8t) = 9t
            *(float4*)&s[9 * t + 4] = w1;
            __syncthreads();
            const int tp = t ^ (j >> 3);
            const float4 pa = *(const float4*)&s[9 * tp];
            const float4 pb = *(const float4*)&s[9 * tp + 4];
            const bool keepmin = (((t & (j >> 3)) == 0) == up);
            const float p[8] = {pa.x, pa.y, pa.z, pa.w, pb.x, pb.y, pb.z, pb.w};
#pragma unroll
            for (int q = 0; q < 8; ++q)
                v[q] = keepmin ? fminf(v[q], p[q]) : fmaxf(v[q], p[q]);
        }
#pragma unroll
        for (int j = 256; j >= 8; j >>= 1) {
            const int  m       = j >> 3;
            const bool keepmin = (((t & m) == 0) == up);
#pragma unroll
            for (int q = 0; q < 8; ++q) {
                const float p = __shfl_xor(v[q], m);
                v[q] = keepmin ? fminf(v[q], p) : fmaxf(v[q], p);
            }
        }
        CE(0, 4, up); CE(1, 5, up); CE(2, 6, up); CE(3, 7, up);
        CE(0, 2, up); CE(1, 3, up); CE(4, 6, up); CE(5, 7, up);
        CE(0, 1, up); CE(2, 3, up); CE(4, 5, up); CE(6, 7, up);
    }
#undef CE

    // ---- publish sorted column to LDS (padded) ----
    __syncthreads();
    {
        float4 w0 = {v[0], v[1], v[2], v[3]};
        float4 w1 = {v[4], v[5], v[6], v[7]};
        *(float4*)&s[9 * t]     = w0;
        *(float4*)&s[9 * t + 4] = w1;
    }
    __syncthreads();

    // ---- stage 2: r_[p] for the thread's 8 sorted positions -------------
    if (v[7] == 0.0f) {
        const float4 z4 = {0.f, 0.f, 0.f, 0.f};
        *(float4*)&r_[9 * t]     = z4;
        *(float4*)&r_[9 * t + 4] = z4;
    } else {
        float rr[8];
#pragma unroll
        for (int q = 0; q < 8; ++q) {
            const int  p  = 8 * t + q;
            const float v0 = v[q];
            int l = p, h = p;
            float sum = v0;  // self
#pragma unroll
            for (int it = 0; it < 5; ++it) {
                const int li = (l > 0) ? l - 1 : 0;
                const int ri = (h < NB - 1) ? h + 1 : NB - 1;
                const float sl = s[PAD(li)];
                const float sr = s[PAD(ri)];
                const float dl = (l > 0) ? (v0 - sl) : 1e30f;
                const float dr = (h < NB - 1) ? (sr - v0) : 1e30f;
                if (dl <= dr) { sum += sl; l = li; }
                else          { sum += sr; h = ri; }
            }
            rr[q] = sum * (1.0f / 6.0f);
        }
        const float4 r0 = {rr[0], rr[1], rr[2], rr[3]};
        const float4 r1 = {rr[4], rr[5], rr[6], rr[7]};
        *(float4*)&r_[9 * t]     = r0;
        *(float4*)&r_[9 * t + 4] = r1;
    }
    __syncthreads();

    // ---- stage 3: per original element, interleaved bsearch + lookup ----
    const float z5 = s[PAD(5)];   // ==0 iff column has >= 6 zeros
    float v0[4];
    bool  zs[4];
    float key[4];
    int   lo[4], hi[4];
#pragma unroll
    for (int w = 0; w < 4; ++w) {
        const int e = half * 2048 + t + w * 512;
        v0[w]  = src[e];
        zs[w]  = (v0[w] == 0.0f) && (z5 == 0.0f);
        key[w] = zs[w] ? -1.0f : v0[w];
        lo[w]  = 0;
        hi[w]  = NB;
    }
#pragma unroll
    for (int step = 0; step < 12; ++step) {
#pragma unroll
        for (int w = 0; w < 4; ++w) {
            const int mid = (lo[w] + hi[w]) >> 1;
            const float sv = s[PAD(mid)];
            if (sv < key[w]) lo[w] = mid + 1; else hi[w] = mid;
        }
    }
#pragma unroll
    for (int w = 0; w < 4; ++w) {
        const int e = half * 2048 + t + w * 512;
        const float res = zs[w] ? 0.0f : r_[PAD(lo[w])];
        prtT[(size_t)col * NB + e] = res;
    }
}

// ---------------------------------------------------------------------------
// Fused tail (512 threads): out = (relu(relu(pr@Wpr^T+bpr)@W2^T+b2))@Wo^T+bo
// Whole Wpr and W2 staged once each. 8 waves/CU (2/SIMD).
// ---------------------------------------------------------------------------
__global__ __launch_bounds__(512) void tail_kernel(const float* __restrict__ AT,
                                                   const float* __restrict__ Wpr,
                                                   const float* __restrict__ bpr,
                                                   const float* __restrict__ W2,
                                                   const float* __restrict__ b2,
                                                   const float* __restrict__ Wo,
                                                   const float* __restrict__ bo,
                                                   float* __restrict__ out)
{
    __shared__ float As[NH1 * 17];    // A^T tile [k=128][m=16]
    __shared__ float Bs[NH1 * 132];   // Wpr full [k][n]; reused for W2 [nn][68]
    __shared__ float Ps[16 * 132];    // pr tile [m][n=128]
    __shared__ float Rs[32 * 32];     // out reduction [g][m*2+o]
    const int tid = threadIdx.x;
    const int m0  = blockIdx.x * 16;

    {   // load A tile: As[k][m] = AT[k*NB + m0 + m]; 512 float4, 1/thread
        const int row = tid >> 2;
        const int f   = (tid & 3) * 4;
        const float4 v = *(const float4*)&AT[(size_t)row * NB + m0 + f];
        As[row * 17 + f + 0] = v.x;
        As[row * 17 + f + 1] = v.y;
        As[row * 17 + f + 2] = v.z;
        As[row * 17 + f + 3] = v.w;
    }
    {   // stage FULL Wpr: Bs[k][n] = Wpr[n][k]; n = tid>>2, k-quarter = tid&3
        const int n  = tid >> 2;
        const int kb = (tid & 3) * 32;
#pragma unroll
        for (int i4 = 0; i4 < 8; ++i4) {
            const float4 v = *(const float4*)&Wpr[(size_t)n * NH1 + kb + i4 * 4];
            Bs[(kb + i4 * 4 + 0) * 132 + n] = v.x;
            Bs[(kb + i4 * 4 + 1) * 132 + n] = v.y;
            Bs[(kb + i4 * 4 + 2) * 132 + n] = v.z;
            Bs[(kb + i4 * 4 + 3) * 132 + n] = v.w;
        }
    }
    __syncthreads();

    const int m  = tid & 15;
    const int g  = tid >> 4;     // 0..31
    const int n0 = g * 4;

    float acc[4] = {0.f, 0.f, 0.f, 0.f};
#pragma unroll 8
    for (int kk = 0; kk < NH1; ++kk) {
        const float a  = As[kk * 17 + m];
        const float4 b = *(const float4*)&Bs[kk * 132 + n0];
        acc[0] = fmaf(a, b.x, acc[0]);
        acc[1] = fmaf(a, b.y, acc[1]);
        acc[2] = fmaf(a, b.z, acc[2]);
        acc[3] = fmaf(a, b.w, acc[3]);
    }
#pragma unroll
    for (int j = 0; j < 4; ++j)
        Ps[m * 132 + n0 + j] = fmaxf(acc[j] + bpr[n0 + j], 0.f);
    __syncthreads();

    {   // stage FULL W2 (reuse Bs): Bs[nn][j2] = W2[j2][nn], stride 68
        const int j2 = tid >> 3;
        const int nb = (tid & 7) * 16;
#pragma unroll
        for (int i4 = 0; i4 < 4; ++i4) {
            const float4 v = *(const float4*)&W2[(size_t)j2 * NH1 + nb + i4 * 4];
            Bs[(nb + i4 * 4 + 0) * 68 + j2] = v.x;
            Bs[(nb + i4 * 4 + 1) * 68 + j2] = v.y;
            Bs[(nb + i4 * 4 + 2) * 68 + j2] = v.z;
            Bs[(nb + i4 * 4 + 3) * 68 + j2] = v.w;
        }
    }
    __syncthreads();

    const int j0 = g * 2;
    float acc2[2] = {0.f, 0.f};
#pragma unroll 8
    for (int nn = 0; nn < NH1; ++nn) {
        const float p  = Ps[m * 132 + nn];
        const float2 w = *(const float2*)&Bs[nn * 68 + j0];
        acc2[0] = fmaf(p, w.x, acc2[0]);
        acc2[1] = fmaf(p, w.y, acc2[1]);
    }

    float po0 = 0.f, po1 = 0.f;
#pragma unroll
    for (int j = 0; j < 2; ++j) {
        const float h = fmaxf(acc2[j] + b2[j0 + j], 0.f);
        po0 = fmaf(h, Wo[j0 + j], po0);
        po1 = fmaf(h, Wo[NH2 + j0 + j], po1);
    }
    Rs[g * 32 + m * 2 + 0] = po0;
    Rs[g * 32 + m * 2 + 1] = po1;
    __syncthreads();
    if (tid < 32) {
        const int mm = tid >> 1, o = tid & 1;
        float sum = 0.f;
#pragma unroll
        for (int gg = 0; gg < 32; ++gg) sum += Rs[gg * 32 + mm * 2 + o];
        out[(size_t)(m0 + mm) * 2 + o] = sum + bo[o];
    }
}

extern "C" void kernel_launch(void* const* d_in, const int* in_sizes, int n_in,
                              void* d_out, int out_size, void* d_ws, size_t ws_size,
                              hipStream_t stream)
{
    const float* x   = (const float*)d_in[0];
    const float* W1  = (const float*)d_in[1];
    const float* b1  = (const float*)d_in[2];
    const float* Wpr = (const float*)d_in[3];
    const float* bpr = (const float*)d_in[4];
    const float* W2  = (const float*)d_in[5];
    const float* b2  = (const float*)d_in[6];
    const float* Wo  = (const float*)d_in[7];
    const float* bo  = (const float*)d_in[8];

    float* ws     = (float*)d_ws;
    float* h1T    = ws;                               // [128][4096]  2 MB
    float* prtT   = h1T + NH1 * NB;                   // [128][4096]  2 MB

    gemm1_mfma<<<dim3(NB / 16), 512, 0, stream>>>(x, W1, b1, h1T);
    sort_window_kernel<<<dim3(NH1 * 2), 512, 0, stream>>>(h1T, prtT);
    tail_kernel<<<dim3(NB / 16), 512, 0, stream>>>(prtT, Wpr, bpr, W2, b2, Wo, bo,
                                                   (float*)d_out);
}

// Round 17
// 47.248 us; speedup vs baseline: 1.4239x; 1.1124x over previous
//
#include <hip/hip_runtime.h>

// PeerNet: out = relu-MLP with per-feature kNN-mean (k=6, 1D) in the middle.
// B=4096, D=1024, H1=128, H2=64, O=2. All fp32.
//
// Pipeline (3 kernels): gemm1 (MFMA f16 hi/lo, in-loop W1 split), sort_window
// v7 (padded LDS), tail v3 (BOTH tail GEMMs on MFMA f16 hi/lo; packed-u32
// hi/lo LDS tiles; scalar GEMM-C + 64-partial reduction).
// [R16 bench was an infra failure (UnresponsiveContainer); resubmitting
//  identical source for a clean measurement.]
//
// Lessons: R2 grid.sync ~30us. R11: rolled loops 2x slower. R12: s-padding
// -65% conflicts. R13: redundant sort regresses (throughput-bound). R14:
// r_ pad null -> sort closed ~19us. R15: prep fused into gemm1 (-4.9us,
// in-loop hi/lo split costs nothing under an L2-bound loop).

#define NB   4096
#define DIN  1024
#define NH1  128
#define NH2  64

// padded LDS index: 8-word groups spaced 9 words -> bank = (9t+q)%32, free
#define PAD(p) ((p) + ((p) >> 3))

typedef _Float16 f16x8 __attribute__((ext_vector_type(8)));
typedef _Float16 f16x4 __attribute__((ext_vector_type(4)));
typedef float    f32x4 __attribute__((ext_vector_type(4)));

__device__ __forceinline__ unsigned pack_hl(float x) {
    const _Float16 h = (_Float16)x;
    const _Float16 l = (_Float16)(x - (float)h);
    unsigned short hu, lu;
    __builtin_memcpy(&hu, &h, 2);
    __builtin_memcpy(&lu, &l, 2);
    return (unsigned)hu | ((unsigned)lu << 16);
}

__device__ __forceinline__ void unpack8(const unsigned* __restrict__ p,
                                        f16x8& hv, f16x8& lv) {
#pragma unroll
    for (int q = 0; q < 8; ++q) {
        const unsigned u = p[q];
        const unsigned short hu = (unsigned short)(u & 0xffffu);
        const unsigned short lu = (unsigned short)(u >> 16);
        _Float16 h, l;
        __builtin_memcpy(&h, &hu, 2);
        __builtin_memcpy(&l, &lu, 2);
        hv[q] = h; lv[q] = l;
    }
}

// ---------------------------------------------------------------------------
// GEMM1 via MFMA 16x16x32 f16, hi/lo split: h1T[n][m] = relu(x@W1^T + b1)^T.
// Grid 256 blocks x 512 threads (8 waves). In-loop W1 fp32->hi/lo split.
// ---------------------------------------------------------------------------
__global__ __launch_bounds__(512) void gemm1_mfma(const float* __restrict__ x,
                                                  const float* __restrict__ W1,
                                                  const float* __restrict__ b1,
                                                  float* __restrict__ h1T)
{
    __shared__ _Float16 xhi[16 * 1032];
    __shared__ _Float16 xlo[16 * 1032];
    const int tid = threadIdx.x;
    const int m0  = blockIdx.x * 16;

    {   // stage + convert: thread t -> row t>>5, cols (t&31)*4 + i*128
        const int r  = tid >> 5;
        const int kb = (tid & 31) * 4;
#pragma unroll
        for (int i = 0; i < 8; ++i) {
            const int k = kb + i * 128;
            const float4 v = *(const float4*)&x[(size_t)(m0 + r) * DIN + k];
            const _Float16 h0 = (_Float16)v.x, h1 = (_Float16)v.y;
            const _Float16 h2 = (_Float16)v.z, h3 = (_Float16)v.w;
            f16x4 hv = {h0, h1, h2, h3};
            f16x4 lv = {(_Float16)(v.x - (float)h0), (_Float16)(v.y - (float)h1),
                        (_Float16)(v.z - (float)h2), (_Float16)(v.w - (float)h3)};
            *(f16x4*)&xhi[r * 1032 + k] = hv;
            *(f16x4*)&xlo[r * 1032 + k] = lv;
        }
    }
    __syncthreads();

    const int lane = tid & 63;
    const int w    = tid >> 6;          // 0..7 -> n-tile
    const int n0   = w * 16;
    const int fr   = lane & 15;
    const int fq   = lane >> 4;         // 0..3

    f32x4 acc = {0.f, 0.f, 0.f, 0.f};
    const float* __restrict__ wp = &W1[(size_t)(n0 + fr) * DIN + fq * 8];
    const _Float16* xh = &xhi[fr * 1032 + fq * 8];
    const _Float16* xl = &xlo[fr * 1032 + fq * 8];

#pragma unroll 4
    for (int ks = 0; ks < 32; ++ks) {
        const int k = ks * 32;
        const f16x8 ah = *(const f16x8*)&xh[k];
        const f16x8 al = *(const f16x8*)&xl[k];
        const float4 wa = *(const float4*)&wp[k];
        const float4 wb = *(const float4*)&wp[k + 4];
        const float wf[8] = {wa.x, wa.y, wa.z, wa.w, wb.x, wb.y, wb.z, wb.w};
        f16x8 bh, bl;
#pragma unroll
        for (int q = 0; q < 8; ++q) {
            const _Float16 h = (_Float16)wf[q];
            bh[q] = h;
            bl[q] = (_Float16)(wf[q] - (float)h);
        }
        acc = __builtin_amdgcn_mfma_f32_16x16x32_f16(ah, bh, acc, 0, 0, 0);
        acc = __builtin_amdgcn_mfma_f32_16x16x32_f16(ah, bl, acc, 0, 0, 0);
        acc = __builtin_amdgcn_mfma_f32_16x16x32_f16(al, bh, acc, 0, 0, 0);
    }

    const int n = n0 + fr;
    const float bv = b1[n];
    float4 o;
    o.x = fmaxf(acc[0] + bv, 0.f);
    o.y = fmaxf(acc[1] + bv, 0.f);
    o.z = fmaxf(acc[2] + bv, 0.f);
    o.w = fmaxf(acc[3] + bv, 0.f);
    *(float4*)&h1T[(size_t)n * NB + m0 + fq * 4] = o;
}

// ---------------------------------------------------------------------------
// sort_window v7 (R15 verbatim): grid 256 = 128 cols x 2 halves, 512 thr.
// ---------------------------------------------------------------------------
__global__ __launch_bounds__(512) void sort_window_kernel(const float* __restrict__ h1T,
                                                          float* __restrict__ prtT)
{
    __shared__ float s[PAD(NB - 1) + 2];    // padded layout
    __shared__ float r_[PAD(NB - 1) + 2];   // padded layout
    const int t    = threadIdx.x;        // 0..511
    const int col  = blockIdx.x >> 1;
    const int half = blockIdx.x & 1;
    const float* __restrict__ src = h1T + (size_t)col * NB;

    float v[8];
    {
        const float4 a = *(const float4*)&src[8 * t];
        const float4 b = *(const float4*)&src[8 * t + 4];
        v[0] = a.x; v[1] = a.y; v[2] = a.z; v[3] = a.w;
        v[4] = b.x; v[5] = b.y; v[6] = b.z; v[7] = b.w;
    }

#define CE(a, b, up)                                        \
    {                                                       \
        const float _x = v[a], _y = v[b];                   \
        v[a] = (up) ? fminf(_x, _y) : fmaxf(_x, _y);        \
        v[b] = (up) ? fmaxf(_x, _y) : fminf(_x, _y);        \
    }

    // ---- k = 2 (j=1) ----
    CE(0, 1, true); CE(2, 3, false); CE(4, 5, true); CE(6, 7, false);
    // ---- k = 4 (j=2,1) ----
    CE(0, 2, true);  CE(1, 3, true);  CE(4, 6, false); CE(5, 7, false);
    CE(0, 1, true);  CE(2, 3, true);  CE(4, 5, false); CE(6, 7, false);

    // ---- k = 8..256: uniform direction per thread ----
#pragma unroll
    for (int k = 8; k <= 256; k <<= 1) {
        const bool up = (t & (k >> 3)) == 0;
#pragma unroll
        for (int j = k >> 1; j >= 8; j >>= 1) {
            const int  m       = j >> 3;
            const bool keepmin = (((t & m) == 0) == up);
#pragma unroll
            for (int q = 0; q < 8; ++q) {
                const float p = __shfl_xor(v[q], m);
                v[q] = keepmin ? fminf(v[q], p) : fmaxf(v[q], p);
            }
        }
        CE(0, 4, up); CE(1, 5, up); CE(2, 6, up); CE(3, 7, up);
        CE(0, 2, up); CE(1, 3, up); CE(4, 6, up); CE(5, 7, up);
        CE(0, 1, up); CE(2, 3, up); CE(4, 5, up); CE(6, 7, up);
    }

    // ---- k = 512..4096: LDS (padded) for j>=512, shfl 256..8, intra 4..1 -
#pragma unroll
    for (int k = 512; k <= 4096; k <<= 1) {
        const bool up = (t & (k >> 3)) == 0;
#pragma unroll
        for (int j = k >> 1; j >= 512; j >>= 1) {
            __syncthreads();
            float4 w0 = {v[0], v[1], v[2], v[3]};
            float4 w1 = {v[4], v[5], v[6], v[7]};
            *(float4*)&s[9 * t]     = w0;      // PAD(8t) = 9t
            *(float4*)&s[9 * t + 4] = w1;
            __syncthreads();
            const int tp = t ^ (j >> 3);
            const float4 pa = *(const float4*)&s[9 * tp];
            const float4 pb = *(const float4*)&s[9 * tp + 4];
            const bool keepmin = (((t & (j >> 3)) == 0) == up);
            const float p[8] = {pa.x, pa.y, pa.z, pa.w, pb.x, pb.y, pb.z, pb.w};
#pragma unroll
            for (int q = 0; q < 8; ++q)
                v[q] = keepmin ? fminf(v[q], p[q]) : fmaxf(v[q], p[q]);
        }
#pragma unroll
        for (int j = 256; j >= 8; j >>= 1) {
            const int  m       = j >> 3;
            const bool keepmin = (((t & m) == 0) == up);
#pragma unroll
            for (int q = 0; q < 8; ++q) {
                const float p = __shfl_xor(v[q], m);
                v[q] = keepmin ? fminf(v[q], p) : fmaxf(v[q], p);
            }
        }
        CE(0, 4, up); CE(1, 5, up); CE(2, 6, up); CE(3, 7, up);
        CE(0, 2, up); CE(1, 3, up); CE(4, 6, up); CE(5, 7, up);
        CE(0, 1, up); CE(2, 3, up); CE(4, 5, up); CE(6, 7, up);
    }
#undef CE

    // ---- publish sorted column to LDS (padded) ----
    __syncthreads();
    {
        float4 w0 = {v[0], v[1], v[2], v[3]};
        float4 w1 = {v[4], v[5], v[6], v[7]};
        *(float4*)&s[9 * t]     = w0;
        *(float4*)&s[9 * t + 4] = w1;
    }
    __syncthreads();

    // ---- stage 2: r_[p] for the thread's 8 sorted positions -------------
    if (v[7] == 0.0f) {
        const float4 z4 = {0.f, 0.f, 0.f, 0.f};
        *(float4*)&r_[9 * t]     = z4;
        *(float4*)&r_[9 * t + 4] = z4;
    } else {
        float rr[8];
#pragma unroll
        for (int q = 0; q < 8; ++q) {
            const int  p  = 8 * t + q;
            const float v0 = v[q];
            int l = p, h = p;
            float sum = v0;  // self
#pragma unroll
            for (int it = 0; it < 5; ++it) {
                const int li = (l > 0) ? l - 1 : 0;
                const int ri = (h < NB - 1) ? h + 1 : NB - 1;
                const float sl = s[PAD(li)];
                const float sr = s[PAD(ri)];
                const float dl = (l > 0) ? (v0 - sl) : 1e30f;
                const float dr = (h < NB - 1) ? (sr - v0) : 1e30f;
                if (dl <= dr) { sum += sl; l = li; }
                else          { sum += sr; h = ri; }
            }
            rr[q] = sum * (1.0f / 6.0f);
        }
        const float4 r0 = {rr[0], rr[1], rr[2], rr[3]};
        const float4 r1 = {rr[4], rr[5], rr[6], rr[7]};
        *(float4*)&r_[9 * t]     = r0;
        *(float4*)&r_[9 * t + 4] = r1;
    }
    __syncthreads();

    // ---- stage 3: per original element, interleaved bsearch + lookup ----
    const float z5 = s[PAD(5)];   // ==0 iff column has >= 6 zeros
    float v0[4];
    bool  zs[4];
    float key[4];
    int   lo[4], hi[4];
#pragma unroll
    for (int w = 0; w < 4; ++w) {
        const int e = half * 2048 + t + w * 512;
        v0[w]  = src[e];
        zs[w]  = (v0[w] == 0.0f) && (z5 == 0.0f);
        key[w] = zs[w] ? -1.0f : v0[w];
        lo[w]  = 0;
        hi[w]  = NB;
    }
#pragma unroll
    for (int step = 0; step < 12; ++step) {
#pragma unroll
        for (int w = 0; w < 4; ++w) {
            const int mid = (lo[w] + hi[w]) >> 1;
            const float sv = s[PAD(mid)];
            if (sv < key[w]) lo[w] = mid + 1; else hi[w] = mid;
        }
    }
#pragma unroll
    for (int w = 0; w < 4; ++w) {
        const int e = half * 2048 + t + w * 512;
        const float res = zs[w] ? 0.0f : r_[PAD(lo[w])];
        prtT[(size_t)col * NB + e] = res;
    }
}

// ---------------------------------------------------------------------------
// tail v3 (512 threads, MFMA): out = (relu(relu(pr@Wpr^T+bpr)@W2^T+b2))@Wo^T+bo
// GEMM A (K=128) and GEMM B (K=128) on mfma_f32_16x16x32_f16 with hi/lo
// split; pr and P tiles live in LDS as packed u32 (hi|lo<<16), stride 132
// (fragment reads 2-way bank aliasing = free). Weights read fp32 from L2
// with in-loop split (proven pattern, R15). GEMM C scalar + 64-partial
// LDS reduction. Fragment mapping mirrors gemm1 exactly.
// ---------------------------------------------------------------------------
__global__ __launch_bounds__(512) void tail_kernel(const float* __restrict__ AT,
                                                   const float* __restrict__ Wpr,
                                                   const float* __restrict__ bpr,
                                                   const float* __restrict__ W2,
                                                   const float* __restrict__ b2,
                                                   const float* __restrict__ Wo,
                                                   const float* __restrict__ bo,
                                                   float* __restrict__ out)
{
    __shared__ unsigned Apk[16 * 132];   // pr tile  [m][k], packed hi/lo
    __shared__ unsigned Ppk[16 * 132];   // P tile   [m][n], packed hi/lo
    __shared__ float    Rs[64 * 32];     // GEMM-C partials [g][m*2+o]
    const int tid = threadIdx.x;
    const int m0  = blockIdx.x * 16;

    {   // stage + convert pr tile: thread: k = tid>>2, f = (tid&3)*4
        const int k = tid >> 2;
        const int f = (tid & 3) * 4;
        const float4 v = *(const float4*)&AT[(size_t)k * NB + m0 + f];
        const float vf[4] = {v.x, v.y, v.z, v.w};
#pragma unroll
        for (int j = 0; j < 4; ++j)
            Apk[(f + j) * 132 + k] = pack_hl(vf[j]);
    }
    __syncthreads();

    const int lane = tid & 63;
    const int w    = tid >> 6;     // 0..7
    const int fr   = lane & 15;
    const int fq   = lane >> 4;    // 0..3

    // ---- GEMM A: P = relu(pr @ Wpr^T + bpr) ------------------------------
    {
        const int n0 = w * 16;
        f32x4 acc = {0.f, 0.f, 0.f, 0.f};
        const float*    __restrict__ wp = &Wpr[(size_t)(n0 + fr) * NH1 + fq * 8];
        const unsigned* __restrict__ ap = &Apk[fr * 132 + fq * 8];
#pragma unroll
        for (int ks = 0; ks < 4; ++ks) {
            const int k = ks * 32;
            f16x8 ah, al;
            unpack8(&ap[k], ah, al);
            const float4 wa = *(const float4*)&wp[k];
            const float4 wb = *(const float4*)&wp[k + 4];
            const float wf[8] = {wa.x, wa.y, wa.z, wa.w, wb.x, wb.y, wb.z, wb.w};
            f16x8 bh, bl;
#pragma unroll
            for (int q = 0; q < 8; ++q) {
                const _Float16 h = (_Float16)wf[q];
                bh[q] = h;
                bl[q] = (_Float16)(wf[q] - (float)h);
            }
            acc = __builtin_amdgcn_mfma_f32_16x16x32_f16(ah, bh, acc, 0, 0, 0);
            acc = __builtin_amdgcn_mfma_f32_16x16x32_f16(ah, bl, acc, 0, 0, 0);
            acc = __builtin_amdgcn_mfma_f32_16x16x32_f16(al, bh, acc, 0, 0, 0);
        }
        const int n = n0 + fr;
        const float bv = bpr[n];
#pragma unroll
        for (int j = 0; j < 4; ++j) {
            const float p = fmaxf(acc[j] + bv, 0.f);
            Ppk[(fq * 4 + j) * 132 + n] = pack_hl(p);
        }
    }
    __syncthreads();

    // ---- GEMM B + C: waves 0..3 (N=64) ----------------------------------
    if (w < 4) {
        const int j0 = w * 16;
        f32x4 acc2 = {0.f, 0.f, 0.f, 0.f};
        const float*    __restrict__ w2p = &W2[(size_t)(j0 + fr) * NH1 + fq * 8];
        const unsigned* __restrict__ pp  = &Ppk[fr * 132 + fq * 8];
#pragma unroll
        for (int ks = 0; ks < 4; ++ks) {
            const int k = ks * 32;
            f16x8 ah, al;
            unpack8(&pp[k], ah, al);
            const float4 wa = *(const float4*)&w2p[k];
            const float4 wb = *(const float4*)&w2p[k + 4];
            const float wf[8] = {wa.x, wa.y, wa.z, wa.w, wb.x, wb.y, wb.z, wb.w};
            f16x8 bh, bl;
#pragma unroll
            for (int q = 0; q < 8; ++q) {
                const _Float16 h = (_Float16)wf[q];
                bh[q] = h;
                bl[q] = (_Float16)(wf[q] - (float)h);
            }
            acc2 = __builtin_amdgcn_mfma_f32_16x16x32_f16(ah, bh, acc2, 0, 0, 0);
            acc2 = __builtin_amdgcn_mfma_f32_16x16x32_f16(ah, bl, acc2, 0, 0, 0);
            acc2 = __builtin_amdgcn_mfma_f32_16x16x32_f16(al, bh, acc2, 0, 0, 0);
        }
        const int jj  = j0 + fr;
        const float b2v = b2[jj];
        const float wo0 = Wo[jj];
        const float wo1 = Wo[NH2 + jj];
        const int g = w * 16 + fr;     // 0..63
#pragma unroll
        for (int j = 0; j < 4; ++j) {
            const float h = fmaxf(acc2[j] + b2v, 0.f);
            const int m = fq * 4 + j;
            Rs[g * 32 + m * 2 + 0] = h * wo0;
            Rs[g * 32 + m * 2 + 1] = h * wo1;
        }
    }
    __syncthreads();

    if (tid < 32) {
        const int mm = tid >> 1, o = tid & 1;
        float sum = 0.f;
#pragma unroll
        for (int g = 0; g < 64; ++g) sum += Rs[g * 32 + mm * 2 + o];
        out[(size_t)(m0 + mm) * 2 + o] = sum + bo[o];
    }
}

extern "C" void kernel_launch(void* const* d_in, const int* in_sizes, int n_in,
                              void* d_out, int out_size, void* d_ws, size_t ws_size,
                              hipStream_t stream)
{
    const float* x   = (const float*)d_in[0];
    const float* W1  = (const float*)d_in[1];
    const float* b1  = (const float*)d_in[2];
    const float* Wpr = (const float*)d_in[3];
    const float* bpr = (const float*)d_in[4];
    const float* W2  = (const float*)d_in[5];
    const float* b2  = (const float*)d_in[6];
    const float* Wo  = (const float*)d_in[7];
    const float* bo  = (const float*)d_in[8];

    float* ws     = (float*)d_ws;
    float* h1T    = ws;                               // [128][4096]  2 MB
    float* prtT   = h1T + NH1 * NB;                   // [128][4096]  2 MB

    gemm1_mfma<<<dim3(NB / 16), 512, 0, stream>>>(x, W1, b1, h1T);
    sort_window_kernel<<<dim3(NH1 * 2), 512, 0, stream>>>(h1T, prtT);
    tail_kernel<<<dim3(NB / 16), 512, 0, stream>>>(prtT, Wpr, bpr, W2, b2, Wo, bo,
                                                   (float*)d_out);
}